// Round 1
// baseline (2392.138 us; speedup 1.0000x reference)
//
#include <hip/hip_runtime.h>
#include <cstdint>
#include <cstddef>

#define ND 256          // embedding dim
#define NK 4096         // num codes
#define NROWS 65536     // 32*2048
#define M_OUT 16777216  // NROWS*ND
#define IDX_OFF (M_OUT + 4)

// ---------------- workspace layout (bytes) ----------------
#define WS_INV64   0                        // double[65536]  512KB
#define WS_INV32   (512*1024)               // float[65536]   256KB
#define WS_E2_32   (WS_INV32 + 256*1024)    // float[4096]    16KB
#define WS_E2_64   (WS_E2_32 + 16*1024)     // double[4096]   32KB
#define WS_BESTIDX (WS_E2_64 + 32*1024)     // int[65536]     256KB
#define WS_COUNTS  (WS_BESTIDX + 256*1024)  // int[4096]      16KB
#define WS_RCOUNT  (WS_COUNTS + 16*1024)    // int[1] + pad   16B
#define WS_RROWS   (WS_RCOUNT + 16)         // int[65536]     256KB
#define WS_PART    (WS_RROWS + 256*1024)    // double[16384]  128KB
// total ~1.45 MB

// ---------------- kernel 1: per-row inverse norms (fp64-accurate) ----------------
__global__ void rownorm_k(const float* __restrict__ z, double* __restrict__ inv64,
                          float* __restrict__ inv32) {
  const int w = threadIdx.x >> 6, lane = threadIdx.x & 63;
  const int row = blockIdx.x * 4 + w;
  const float4 v = *reinterpret_cast<const float4*>(z + (size_t)row * ND + lane * 4);
  double s = (double)v.x * v.x + (double)v.y * v.y + (double)v.z * v.z + (double)v.w * v.w;
  #pragma unroll
  for (int m = 32; m; m >>= 1) s += __shfl_xor(s, m, 64);
  if (lane == 0) {
    double nrm = sqrt(s);
    if (nrm < 1e-12) nrm = 1e-12;
    const double inv = 1.0 / nrm;
    inv64[row] = inv;
    inv32[row] = (float)inv;
  }
}

// ---------------- kernel 2: per-code squared norms ----------------
__global__ void embnorm_k(const float* __restrict__ e, float* __restrict__ e2_32,
                          double* __restrict__ e2_64) {
  const int w = threadIdx.x >> 6, lane = threadIdx.x & 63;
  const int row = blockIdx.x * 4 + w;
  const float4 v = *reinterpret_cast<const float4*>(e + (size_t)row * ND + lane * 4);
  double s = (double)v.x * v.x + (double)v.y * v.y + (double)v.z * v.z + (double)v.w * v.w;
  #pragma unroll
  for (int m = 32; m; m >>= 1) s += __shfl_xor(s, m, 64);
  if (lane == 0) {
    e2_64[row] = s;
    e2_32[row] = (float)s;
  }
}

// ---------------- kernel 3: fused fp32 GEMM + argmin (+2nd best) ----------------
#define DK 32
#define MB 128
#define NB 256
#define ASTR 132   // padded row stride for As[d][row]  (528B: 16B-aligned, conflict-mitigating)
#define BSTR 260   // padded row stride for Bs[d][code] (1040B: 16B-aligned)
#define MARGIN 1e-4f

__launch_bounds__(256, 2)
__global__ void phase1_k(const float* __restrict__ z, const float* __restrict__ emb,
                         const float* __restrict__ e2, const float* __restrict__ inv32,
                         int* __restrict__ best_idx, int* __restrict__ rcount,
                         int* __restrict__ rrows) {
  __shared__ float smem[DK * ASTR + DK * BSTR];  // 50176 B
  float* As = smem;
  float* Bs = smem + DK * ASTR;
  const int t = threadIdx.x;
  const int tx = t & 15, ty = t >> 4;
  const int row0 = blockIdx.x * MB;

  float b1[8], b2[8], invn[8];
  int i1[8];
  #pragma unroll
  for (int i = 0; i < 8; ++i) {
    b1[i] = 3.4e38f; b2[i] = 3.4e38f; i1[i] = 0;
    invn[i] = inv32[row0 + ty * 8 + i];
  }

  for (int tile = 0; tile < NK / NB; ++tile) {
    const int cbase = tile * NB;
    float acc[8][16];
    #pragma unroll
    for (int i = 0; i < 8; ++i)
      #pragma unroll
      for (int j = 0; j < 16; ++j) acc[i][j] = 0.f;

    for (int ks = 0; ks < ND / DK; ++ks) {
      const int d0 = ks * DK;
      __syncthreads();
      // stage A tile (128 rows x 32 d), transposed into As[d][row]
      #pragma unroll
      for (int it = 0; it < 4; ++it) {
        const int u = it * 256 + t;
        const int r = u >> 3, ch = u & 7;
        const float4 v = *reinterpret_cast<const float4*>(
            z + (size_t)(row0 + r) * ND + d0 + ch * 4);
        As[(ch * 4 + 0) * ASTR + r] = v.x;
        As[(ch * 4 + 1) * ASTR + r] = v.y;
        As[(ch * 4 + 2) * ASTR + r] = v.z;
        As[(ch * 4 + 3) * ASTR + r] = v.w;
      }
      // stage B tile (256 codes x 32 d), transposed into Bs[d][code]
      #pragma unroll
      for (int it = 0; it < 8; ++it) {
        const int u = it * 256 + t;
        const int c = u >> 3, ch = u & 7;
        const float4 v = *reinterpret_cast<const float4*>(
            emb + (size_t)(cbase + c) * ND + d0 + ch * 4);
        Bs[(ch * 4 + 0) * BSTR + c] = v.x;
        Bs[(ch * 4 + 1) * BSTR + c] = v.y;
        Bs[(ch * 4 + 2) * BSTR + c] = v.z;
        Bs[(ch * 4 + 3) * BSTR + c] = v.w;
      }
      __syncthreads();
      #pragma unroll 8
      for (int d = 0; d < DK; ++d) {
        const float4 a0 = *reinterpret_cast<const float4*>(&As[d * ASTR + ty * 8]);
        const float4 a1 = *reinterpret_cast<const float4*>(&As[d * ASTR + ty * 8 + 4]);
        float4 bv[4];
        #pragma unroll
        for (int g = 0; g < 4; ++g)
          bv[g] = *reinterpret_cast<const float4*>(&Bs[d * BSTR + tx * 4 + 64 * g]);
        const float a[8] = {a0.x, a0.y, a0.z, a0.w, a1.x, a1.y, a1.z, a1.w};
        #pragma unroll
        for (int i = 0; i < 8; ++i) {
          #pragma unroll
          for (int g = 0; g < 4; ++g) {
            acc[i][g * 4 + 0] += a[i] * bv[g].x;
            acc[i][g * 4 + 1] += a[i] * bv[g].y;
            acc[i][g * 4 + 2] += a[i] * bv[g].z;
            acc[i][g * 4 + 3] += a[i] * bv[g].w;
          }
        }
      }
    }
    // epilogue: scores (e2 - 2*invn*dot_raw), running best/2nd best, ascending code order
    #pragma unroll
    for (int i = 0; i < 8; ++i) {
      #pragma unroll
      for (int g = 0; g < 4; ++g) {
        #pragma unroll
        for (int q = 0; q < 4; ++q) {
          const int c = cbase + 64 * g + tx * 4 + q;
          const float s = e2[c] - 2.0f * invn[i] * acc[i][g * 4 + q];
          if (s < b1[i]) { b2[i] = b1[i]; b1[i] = s; i1[i] = c; }
          else if (s < b2[i]) { b2[i] = s; }
        }
      }
    }
  }

  // cross-thread merge (16 tx threads share each row), explicit index tie-break
  __syncthreads();
  float* S1 = smem;
  int*   SI = (int*)(smem + 2048);
  float* S2 = smem + 4096;
  #pragma unroll
  for (int i = 0; i < 8; ++i) {
    const int rl = ty * 8 + i;
    S1[rl * 16 + tx] = b1[i];
    SI[rl * 16 + tx] = i1[i];
    S2[rl * 16 + tx] = b2[i];
  }
  __syncthreads();
  if (t < MB) {
    float B1 = 3.4e38f, B2 = 3.4e38f;
    int I1 = 0x7fffffff;
    for (int k = 0; k < 16; ++k) {
      const float s = S1[t * 16 + k];
      const int idx = SI[t * 16 + k];
      const float s2 = S2[t * 16 + k];
      if (s < B1 || (s == B1 && idx < I1)) {
        B2 = (B1 < s2) ? B1 : s2;  // old best becomes 2nd-best candidate
        B1 = s; I1 = idx;
      } else {
        B2 = (B2 < s) ? B2 : s;
      }
    }
    const int row = row0 + t;
    best_idx[row] = I1;
    if (B2 - B1 < MARGIN) {       // ambiguous at fp32 precision -> exact recheck
      const int pos = atomicAdd(rcount, 1);
      rrows[pos] = row;
    }
  }
}

// ---------------- kernel 4: exact fp64 recheck of flagged rows ----------------
__global__ void phase2_k(const float* __restrict__ z, const float* __restrict__ emb,
                         const double* __restrict__ e2_64, const double* __restrict__ inv64,
                         const int* __restrict__ rcount, const int* __restrict__ rrows,
                         int* __restrict__ best_idx) {
  __shared__ double zn[ND];
  __shared__ double RB[256];
  __shared__ int RI[256];
  const int t = threadIdx.x;
  int cnt = rcount[0];
  if (cnt > NROWS) cnt = NROWS;
  for (int e = blockIdx.x; e < cnt; e += gridDim.x) {
    const int row = rrows[e];
    __syncthreads();
    zn[t] = (double)z[(size_t)row * ND + t] * inv64[row];
    __syncthreads();
    double B1 = 1e300;
    int I1 = 0;
    for (int c0 = 0; c0 < 16; ++c0) {
      const int c = t * 16 + c0;  // ascending within thread -> lowest-index on tie
      const float* er = emb + (size_t)c * ND;
      double dot = 0.0;
      for (int d = 0; d < ND; d += 4) {
        const float4 ev = *reinterpret_cast<const float4*>(er + d);
        dot += zn[d] * (double)ev.x + zn[d + 1] * (double)ev.y +
               zn[d + 2] * (double)ev.z + zn[d + 3] * (double)ev.w;
      }
      const double s = e2_64[c] - 2.0 * dot;
      if (s < B1) { B1 = s; I1 = c; }
    }
    RB[t] = B1; RI[t] = I1;
    __syncthreads();
    for (int off = 128; off; off >>= 1) {
      if (t < off) {
        const double sb = RB[t + off];
        const int si = RI[t + off];
        if (sb < RB[t] || (sb == RB[t] && si < RI[t])) { RB[t] = sb; RI[t] = si; }
      }
      __syncthreads();
    }
    if (t == 0) best_idx[row] = RI[0];
  }
}

// ---------------- kernel 5: gather z_q, loss partials, histogram, index output ----------------
__global__ void gather_k(const float* __restrict__ z, const float* __restrict__ emb,
                         const int* __restrict__ best_idx, const double* __restrict__ inv64,
                         float* __restrict__ out, double* __restrict__ partials,
                         int* __restrict__ counts) {
  __shared__ double wsum[4];
  const int w = threadIdx.x >> 6, lane = threadIdx.x & 63;
  const int row = blockIdx.x * 4 + w;
  const int idx = best_idx[row];
  const double inv = inv64[row];
  const float4 zv = *reinterpret_cast<const float4*>(z + (size_t)row * ND + lane * 4);
  const float4 ev = *reinterpret_cast<const float4*>(emb + (size_t)idx * ND + lane * 4);
  *reinterpret_cast<float4*>(out + (size_t)row * ND + lane * 4) = ev;  // z_q_st == z_q
  const double dx = (double)ev.x - (double)zv.x * inv;
  const double dy = (double)ev.y - (double)zv.y * inv;
  const double dz = (double)ev.z - (double)zv.z * inv;
  const double dw = (double)ev.w - (double)zv.w * inv;
  double s = dx * dx + dy * dy + dz * dz + dw * dw;
  #pragma unroll
  for (int m = 32; m; m >>= 1) s += __shfl_xor(s, m, 64);
  if (lane == 0) {
    wsum[w] = s;
    atomicAdd(&counts[idx], 1);
    out[IDX_OFF + row] = (float)idx;
  }
  __syncthreads();
  if (threadIdx.x == 0) partials[blockIdx.x] = wsum[0] + wsum[1] + wsum[2] + wsum[3];
}

// ---------------- kernel 6: scalars (losses + perplexity) ----------------
__global__ void finalize_k(const double* __restrict__ partials, const int* __restrict__ counts,
                           float* __restrict__ out) {
  __shared__ double red[256];
  const int t = threadIdx.x;
  double s = 0.0;
  for (int k = 0; k < 64; ++k) s += partials[t + 256 * k];
  red[t] = s;
  __syncthreads();
  for (int off = 128; off; off >>= 1) {
    if (t < off) red[t] += red[t + off];
    __syncthreads();
  }
  const double c = red[0] / (double)M_OUT;  // codebook_loss == commitment_loss
  __syncthreads();
  double h = 0.0;
  for (int k = 0; k < 16; ++k) {
    const double p = (double)counts[t * 16 + k] * (1.0 / 65536.0);
    h += p * log(p + 1e-10);
  }
  red[t] = h;
  __syncthreads();
  for (int off = 128; off; off >>= 1) {
    if (t < off) red[t] += red[t + off];
    __syncthreads();
  }
  if (t == 0) {
    const double perp = exp(-red[0]);
    out[M_OUT + 0] = (float)(c + 0.25 * c);  // vq_loss = codebook + BETA*commitment
    out[M_OUT + 1] = (float)c;               // codebook_loss
    out[M_OUT + 2] = (float)c;               // commitment_loss
    out[M_OUT + 3] = (float)perp;            // perplexity
  }
}

extern "C" void kernel_launch(void* const* d_in, const int* in_sizes, int n_in,
                              void* d_out, int out_size, void* d_ws, size_t ws_size,
                              hipStream_t stream) {
  const float* z = (const float*)d_in[0];
  const float* emb = (const float*)d_in[1];
  float* out = (float*)d_out;
  char* ws = (char*)d_ws;
  double* inv64   = (double*)(ws + WS_INV64);
  float*  inv32   = (float*)(ws + WS_INV32);
  float*  e2_32   = (float*)(ws + WS_E2_32);
  double* e2_64   = (double*)(ws + WS_E2_64);
  int*    best_i  = (int*)(ws + WS_BESTIDX);
  int*    counts  = (int*)(ws + WS_COUNTS);
  int*    rcount  = (int*)(ws + WS_RCOUNT);
  int*    rrows   = (int*)(ws + WS_RROWS);
  double* partials = (double*)(ws + WS_PART);

  hipMemsetAsync(ws + WS_COUNTS, 0, 16 * 1024 + 16, stream);  // counts + rcount
  rownorm_k<<<NROWS / 4, 256, 0, stream>>>(z, inv64, inv32);
  embnorm_k<<<NK / 4, 256, 0, stream>>>(emb, e2_32, e2_64);
  phase1_k<<<NROWS / MB, 256, 0, stream>>>(z, emb, e2_32, inv32, best_i, rcount, rrows);
  phase2_k<<<1024, 256, 0, stream>>>(z, emb, e2_64, inv64, rcount, rrows, best_i);
  gather_k<<<NROWS / 4, 256, 0, stream>>>(z, emb, best_i, inv64, out, partials, counts);
  finalize_k<<<1, 256, 0, stream>>>(partials, counts, out);
}

// Round 2
// 1718.218 us; speedup vs baseline: 1.3922x; 1.3922x over previous
//
#include <hip/hip_runtime.h>
#include <cstdint>
#include <cstddef>

#define ND 256          // embedding dim
#define NK 4096         // num codes
#define NROWS 65536     // 32*2048
#define M_OUT 16777216  // NROWS*ND
#define IDX_OFF (M_OUT + 4)

// ---------------- workspace layout (bytes) ----------------
#define WS_INV64   0                        // double[65536]  512KB
#define WS_INV32   (512*1024)               // float[65536]   256KB
#define WS_E2_32   (WS_INV32 + 256*1024)    // float[4096]    16KB
#define WS_E2_64   (WS_E2_32 + 16*1024)     // double[4096]   32KB
#define WS_BESTIDX (WS_E2_64 + 32*1024)     // int[65536]     256KB
#define WS_COUNTS  (WS_BESTIDX + 256*1024)  // int[4096]      16KB
#define WS_RCOUNT  (WS_COUNTS + 16*1024)    // int[1] + pad   16B
#define WS_RROWS   (WS_RCOUNT + 16)         // int[65536]     256KB
#define WS_PART    (WS_RROWS + 256*1024)    // double[16384]  128KB

typedef __attribute__((ext_vector_type(8))) short bf16x8;
typedef __attribute__((ext_vector_type(4))) float f32x4;

__device__ __forceinline__ unsigned short f2bf(float f) {
  union { float f; unsigned int u; } c; c.f = f;
  unsigned int u = c.u + 0x7fffu + ((c.u >> 16) & 1u);  // RNE
  return (unsigned short)(u >> 16);
}
__device__ __forceinline__ float bf2f(unsigned short h) {
  union { unsigned int u; float f; } c; c.u = ((unsigned int)h) << 16;
  return c.f;
}

// ---------------- kernel 1: per-row inverse norms (fp64-accurate) ----------------
__global__ void rownorm_k(const float* __restrict__ z, double* __restrict__ inv64,
                          float* __restrict__ inv32) {
  const int w = threadIdx.x >> 6, lane = threadIdx.x & 63;
  const int row = blockIdx.x * 4 + w;
  const float4 v = *reinterpret_cast<const float4*>(z + (size_t)row * ND + lane * 4);
  double s = (double)v.x * v.x + (double)v.y * v.y + (double)v.z * v.z + (double)v.w * v.w;
  #pragma unroll
  for (int m = 32; m; m >>= 1) s += __shfl_xor(s, m, 64);
  if (lane == 0) {
    double nrm = sqrt(s);
    if (nrm < 1e-12) nrm = 1e-12;
    const double inv = 1.0 / nrm;
    inv64[row] = inv;
    inv32[row] = (float)inv;
  }
}

// ---------------- kernel 2: per-code squared norms ----------------
__global__ void embnorm_k(const float* __restrict__ e, float* __restrict__ e2_32,
                          double* __restrict__ e2_64) {
  const int w = threadIdx.x >> 6, lane = threadIdx.x & 63;
  const int row = blockIdx.x * 4 + w;
  const float4 v = *reinterpret_cast<const float4*>(e + (size_t)row * ND + lane * 4);
  double s = (double)v.x * v.x + (double)v.y * v.y + (double)v.z * v.z + (double)v.w * v.w;
  #pragma unroll
  for (int m = 32; m; m >>= 1) s += __shfl_xor(s, m, 64);
  if (lane == 0) {
    e2_64[row] = s;
    e2_32[row] = (float)s;
  }
}

// ---------------- kernel 3: split-bf16 MFMA GEMM + argmin (+2nd best) ----------------
// 128 rows x 128 codes per block; K=256 in 4 chunks of 64; 4 waves (2x2),
// each wave 64x64 = 4x4 MFMA(16x16x32) tiles; acc = Ah*Bh + Ah*Bl + Al*Bh.
#define MB 128
#define NB 128
#define BK 64
#define LSTR 72        // LDS row stride in ushorts (144 B: 16B-aligned, 2-way banks = free)
#define MARGIN 3e-4f

__launch_bounds__(256, 2)
__global__ void phase1_k(const float* __restrict__ z, const float* __restrict__ emb,
                         const float* __restrict__ e2, const float* __restrict__ inv32,
                         int* __restrict__ best_idx, int* __restrict__ rcount,
                         int* __restrict__ rrows) {
  __shared__ __align__(16) unsigned short smem[4 * MB * LSTR];  // 73728 B
  unsigned short* Ah = smem;
  unsigned short* Al = smem + MB * LSTR;
  unsigned short* Bh = smem + 2 * MB * LSTR;
  unsigned short* Bl = smem + 3 * MB * LSTR;

  const int t = threadIdx.x;
  const int l = t & 63;
  const int wave = t >> 6;
  const int wm = wave & 1;   // row half
  const int wn = wave >> 1;  // code half
  const int l15 = l & 15, l4 = l >> 4;
  const int row0 = blockIdx.x * MB;

  float b1[16], b2[16];
  int i1[16];
  #pragma unroll
  for (int s = 0; s < 16; ++s) { b1[s] = 3.4e38f; b2[s] = 3.4e38f; i1[s] = 0; }

  for (int ct = 0; ct < NK / NB; ++ct) {
    const int cbase = ct * NB;
    f32x4 acc[4][4];
    #pragma unroll
    for (int mt = 0; mt < 4; ++mt)
      #pragma unroll
      for (int nt = 0; nt < 4; ++nt) acc[mt][nt] = (f32x4){0.f, 0.f, 0.f, 0.f};

    for (int ks = 0; ks < ND / BK; ++ks) {
      const int d0 = ks * BK;
      __syncthreads();
      // stage A (128 rows x 64 k): fp32 -> normalized -> bf16 hi/lo
      #pragma unroll
      for (int it = 0; it < 8; ++it) {
        const int idx = it * 256 + t;
        const int r = idx >> 4, sg = idx & 15;
        const int zrow = row0 + r;
        float4 v = *reinterpret_cast<const float4*>(z + (size_t)zrow * ND + d0 + sg * 4);
        const float sc = inv32[zrow];
        v.x *= sc; v.y *= sc; v.z *= sc; v.w *= sc;
        ushort4 h, lo;
        h.x = f2bf(v.x); h.y = f2bf(v.y); h.z = f2bf(v.z); h.w = f2bf(v.w);
        lo.x = f2bf(v.x - bf2f(h.x)); lo.y = f2bf(v.y - bf2f(h.y));
        lo.z = f2bf(v.z - bf2f(h.z)); lo.w = f2bf(v.w - bf2f(h.w));
        *reinterpret_cast<ushort4*>(&Ah[r * LSTR + sg * 4]) = h;
        *reinterpret_cast<ushort4*>(&Al[r * LSTR + sg * 4]) = lo;
      }
      // stage B (128 codes x 64 k): fp32 -> bf16 hi/lo
      #pragma unroll
      for (int it = 0; it < 8; ++it) {
        const int idx = it * 256 + t;
        const int r = idx >> 4, sg = idx & 15;
        const float4 v = *reinterpret_cast<const float4*>(
            emb + (size_t)(cbase + r) * ND + d0 + sg * 4);
        ushort4 h, lo;
        h.x = f2bf(v.x); h.y = f2bf(v.y); h.z = f2bf(v.z); h.w = f2bf(v.w);
        lo.x = f2bf(v.x - bf2f(h.x)); lo.y = f2bf(v.y - bf2f(h.y));
        lo.z = f2bf(v.z - bf2f(h.z)); lo.w = f2bf(v.w - bf2f(h.w));
        *reinterpret_cast<ushort4*>(&Bh[r * LSTR + sg * 4]) = h;
        *reinterpret_cast<ushort4*>(&Bl[r * LSTR + sg * 4]) = lo;
      }
      __syncthreads();
      #pragma unroll
      for (int kk = 0; kk < 2; ++kk) {
        const int ko = kk * 32 + l4 * 8;
        bf16x8 aH[4], aL[4], bH[4], bL[4];
        #pragma unroll
        for (int mt = 0; mt < 4; ++mt) {
          const int ar = wm * 64 + mt * 16 + l15;
          aH[mt] = *reinterpret_cast<const bf16x8*>(&Ah[ar * LSTR + ko]);
          aL[mt] = *reinterpret_cast<const bf16x8*>(&Al[ar * LSTR + ko]);
        }
        #pragma unroll
        for (int nt = 0; nt < 4; ++nt) {
          const int br = wn * 64 + nt * 16 + l15;
          bH[nt] = *reinterpret_cast<const bf16x8*>(&Bh[br * LSTR + ko]);
          bL[nt] = *reinterpret_cast<const bf16x8*>(&Bl[br * LSTR + ko]);
        }
        #pragma unroll
        for (int mt = 0; mt < 4; ++mt)
          #pragma unroll
          for (int nt = 0; nt < 4; ++nt) {
            acc[mt][nt] = __builtin_amdgcn_mfma_f32_16x16x32_bf16(aH[mt], bH[nt], acc[mt][nt], 0, 0, 0);
            acc[mt][nt] = __builtin_amdgcn_mfma_f32_16x16x32_bf16(aH[mt], bL[nt], acc[mt][nt], 0, 0, 0);
            acc[mt][nt] = __builtin_amdgcn_mfma_f32_16x16x32_bf16(aL[mt], bH[nt], acc[mt][nt], 0, 0, 0);
          }
      }
    }
    // epilogue: score = e2 - 2*dot; per-lane best/2nd, ascending code order
    #pragma unroll
    for (int nt = 0; nt < 4; ++nt) {
      const int c = cbase + wn * 64 + nt * 16 + l15;
      const float e2c = e2[c];
      #pragma unroll
      for (int mt = 0; mt < 4; ++mt) {
        #pragma unroll
        for (int r = 0; r < 4; ++r) {
          const float s = fmaf(-2.0f, acc[mt][nt][r], e2c);
          const int slot = mt * 4 + r;
          if (s < b1[slot]) { b2[slot] = b1[slot]; b1[slot] = s; i1[slot] = c; }
          else if (s < b2[slot]) { b2[slot] = s; }
        }
      }
    }
  }

  // butterfly merge across the 16 lanes (l&15) sharing each row
  #pragma unroll
  for (int s = 0; s < 16; ++s) {
    #pragma unroll
    for (int m = 1; m < 16; m <<= 1) {
      const float ob1 = __shfl_xor(b1[s], m, 64);
      const float ob2 = __shfl_xor(b2[s], m, 64);
      const int oi1 = __shfl_xor(i1[s], m, 64);
      if (ob1 < b1[s] || (ob1 == b1[s] && oi1 < i1[s])) {
        b2[s] = fminf(b1[s], ob2);
        b1[s] = ob1; i1[s] = oi1;
      } else {
        b2[s] = fminf(b2[s], ob1);
      }
    }
  }

  // cross-wave (wn=0/1) merge via small LDS
  __syncthreads();
  float* M1 = (float*)smem;           // [128][2]
  float* M2 = M1 + 256;               // [128][2]
  int*   MI = (int*)(M1 + 512);       // [128][2]
  if (l15 == 0) {
    #pragma unroll
    for (int s = 0; s < 16; ++s) {
      const int mt = s >> 2, r = s & 3;
      const int rl = wm * 64 + mt * 16 + l4 * 4 + r;
      M1[rl * 2 + wn] = b1[s];
      M2[rl * 2 + wn] = b2[s];
      MI[rl * 2 + wn] = i1[s];
    }
  }
  __syncthreads();
  if (t < MB) {
    float B1 = M1[t * 2], B2 = M2[t * 2];
    int I1 = MI[t * 2];
    const float y1 = M1[t * 2 + 1], y2 = M2[t * 2 + 1];
    const int yi = MI[t * 2 + 1];
    if (y1 < B1 || (y1 == B1 && yi < I1)) {
      B2 = fminf(B1, y2);
      B1 = y1; I1 = yi;
    } else {
      B2 = fminf(B2, y1);
    }
    const int row = row0 + t;
    best_idx[row] = I1;
    if (B2 - B1 < MARGIN) {  // ambiguous at split-bf16 precision -> exact recheck
      const int pos = atomicAdd(rcount, 1);
      rrows[pos] = row;
    }
  }
}

// ---------------- kernel 4: exact fp64 recheck of flagged rows ----------------
__global__ void phase2_k(const float* __restrict__ z, const float* __restrict__ emb,
                         const double* __restrict__ e2_64, const double* __restrict__ inv64,
                         const int* __restrict__ rcount, const int* __restrict__ rrows,
                         int* __restrict__ best_idx) {
  __shared__ double zn[ND];
  __shared__ double RB[256];
  __shared__ int RI[256];
  const int t = threadIdx.x;
  int cnt = rcount[0];
  if (cnt > NROWS) cnt = NROWS;
  for (int e = blockIdx.x; e < cnt; e += gridDim.x) {
    const int row = rrows[e];
    __syncthreads();
    zn[t] = (double)z[(size_t)row * ND + t] * inv64[row];
    __syncthreads();
    double B1 = 1e300;
    int I1 = 0;
    for (int c0 = 0; c0 < 16; ++c0) {
      const int c = t * 16 + c0;  // ascending within thread -> lowest-index on tie
      const float* er = emb + (size_t)c * ND;
      double dot = 0.0;
      for (int d = 0; d < ND; d += 4) {
        const float4 ev = *reinterpret_cast<const float4*>(er + d);
        dot += zn[d] * (double)ev.x + zn[d + 1] * (double)ev.y +
               zn[d + 2] * (double)ev.z + zn[d + 3] * (double)ev.w;
      }
      const double s = e2_64[c] - 2.0 * dot;
      if (s < B1) { B1 = s; I1 = c; }
    }
    RB[t] = B1; RI[t] = I1;
    __syncthreads();
    for (int off = 128; off; off >>= 1) {
      if (t < off) {
        const double sb = RB[t + off];
        const int si = RI[t + off];
        if (sb < RB[t] || (sb == RB[t] && si < RI[t])) { RB[t] = sb; RI[t] = si; }
      }
      __syncthreads();
    }
    if (t == 0) best_idx[row] = RI[0];
  }
}

// ---------------- kernel 5: gather z_q, loss partials, histogram, index output ----------------
__global__ void gather_k(const float* __restrict__ z, const float* __restrict__ emb,
                         const int* __restrict__ best_idx, const double* __restrict__ inv64,
                         float* __restrict__ out, double* __restrict__ partials,
                         int* __restrict__ counts) {
  __shared__ double wsum[4];
  const int w = threadIdx.x >> 6, lane = threadIdx.x & 63;
  const int row = blockIdx.x * 4 + w;
  const int idx = best_idx[row];
  const double inv = inv64[row];
  const float4 zv = *reinterpret_cast<const float4*>(z + (size_t)row * ND + lane * 4);
  const float4 ev = *reinterpret_cast<const float4*>(emb + (size_t)idx * ND + lane * 4);
  *reinterpret_cast<float4*>(out + (size_t)row * ND + lane * 4) = ev;  // z_q_st == z_q
  const double dx = (double)ev.x - (double)zv.x * inv;
  const double dy = (double)ev.y - (double)zv.y * inv;
  const double dz = (double)ev.z - (double)zv.z * inv;
  const double dw = (double)ev.w - (double)zv.w * inv;
  double s = dx * dx + dy * dy + dz * dz + dw * dw;
  #pragma unroll
  for (int m = 32; m; m >>= 1) s += __shfl_xor(s, m, 64);
  if (lane == 0) {
    wsum[w] = s;
    atomicAdd(&counts[idx], 1);
    out[IDX_OFF + row] = (float)idx;
  }
  __syncthreads();
  if (threadIdx.x == 0) partials[blockIdx.x] = wsum[0] + wsum[1] + wsum[2] + wsum[3];
}

// ---------------- kernel 6: scalars (losses + perplexity) ----------------
__global__ void finalize_k(const double* __restrict__ partials, const int* __restrict__ counts,
                           float* __restrict__ out) {
  __shared__ double red[256];
  const int t = threadIdx.x;
  double s = 0.0;
  for (int k = 0; k < 64; ++k) s += partials[t + 256 * k];
  red[t] = s;
  __syncthreads();
  for (int off = 128; off; off >>= 1) {
    if (t < off) red[t] += red[t + off];
    __syncthreads();
  }
  const double c = red[0] / (double)M_OUT;  // codebook_loss == commitment_loss
  __syncthreads();
  double h = 0.0;
  for (int k = 0; k < 16; ++k) {
    const double p = (double)counts[t * 16 + k] * (1.0 / 65536.0);
    h += p * log(p + 1e-10);
  }
  red[t] = h;
  __syncthreads();
  for (int off = 128; off; off >>= 1) {
    if (t < off) red[t] += red[t + off];
    __syncthreads();
  }
  if (t == 0) {
    const double perp = exp(-red[0]);
    out[M_OUT + 0] = (float)(c + 0.25 * c);  // vq_loss = codebook + BETA*commitment
    out[M_OUT + 1] = (float)c;               // codebook_loss
    out[M_OUT + 2] = (float)c;               // commitment_loss
    out[M_OUT + 3] = (float)perp;            // perplexity
  }
}

extern "C" void kernel_launch(void* const* d_in, const int* in_sizes, int n_in,
                              void* d_out, int out_size, void* d_ws, size_t ws_size,
                              hipStream_t stream) {
  const float* z = (const float*)d_in[0];
  const float* emb = (const float*)d_in[1];
  float* out = (float*)d_out;
  char* ws = (char*)d_ws;
  double* inv64   = (double*)(ws + WS_INV64);
  float*  inv32   = (float*)(ws + WS_INV32);
  float*  e2_32   = (float*)(ws + WS_E2_32);
  double* e2_64   = (double*)(ws + WS_E2_64);
  int*    best_i  = (int*)(ws + WS_BESTIDX);
  int*    counts  = (int*)(ws + WS_COUNTS);
  int*    rcount  = (int*)(ws + WS_RCOUNT);
  int*    rrows   = (int*)(ws + WS_RROWS);
  double* partials = (double*)(ws + WS_PART);

  hipMemsetAsync(ws + WS_COUNTS, 0, 16 * 1024 + 16, stream);  // counts + rcount
  rownorm_k<<<NROWS / 4, 256, 0, stream>>>(z, inv64, inv32);
  embnorm_k<<<NK / 4, 256, 0, stream>>>(emb, e2_32, e2_64);
  phase1_k<<<NROWS / MB, 256, 0, stream>>>(z, emb, e2_32, inv32, best_i, rcount, rrows);
  phase2_k<<<1024, 256, 0, stream>>>(z, emb, e2_64, inv64, rcount, rrows, best_i);
  gather_k<<<NROWS / 4, 256, 0, stream>>>(z, emb, best_i, inv64, out, partials, counts);
  finalize_k<<<1, 256, 0, stream>>>(partials, counts, out);
}

// Round 3
// 1109.859 us; speedup vs baseline: 2.1554x; 1.5481x over previous
//
#include <hip/hip_runtime.h>
#include <cstdint>
#include <cstddef>

#define ND 256          // embedding dim
#define NK 4096         // num codes
#define NROWS 65536     // 32*2048
#define M_OUT 16777216  // NROWS*ND
#define IDX_OFF (M_OUT + 4)

// ---------------- workspace layout (bytes) ----------------
#define WS_INV64   0                        // double[65536]  512KB
#define WS_E2_32   (512*1024)               // float[4096]    16KB
#define WS_E2_64   (WS_E2_32 + 16*1024)     // double[4096]   32KB
#define WS_EHI     (WS_E2_64 + 32*1024)     // ushort[1M]     2MB
#define WS_ELO     (WS_EHI + 2*1024*1024)   // ushort[1M]     2MB
#define WS_BESTIDX (WS_ELO + 2*1024*1024)   // int[65536]     256KB
#define WS_COUNTS  (WS_BESTIDX + 256*1024)  // int[4096]      16KB
#define WS_RCOUNT  (WS_COUNTS + 16*1024)    // int[1] + pad   16B
#define WS_RROWS   (WS_RCOUNT + 16)         // int[65536]     256KB
#define WS_PART    (WS_RROWS + 256*1024)    // double[16384]  128KB
// total ~5.7 MB

typedef __attribute__((ext_vector_type(8))) short bf16x8;
typedef __attribute__((ext_vector_type(4))) float f32x4;

__device__ __forceinline__ unsigned short f2bf(float f) {
  union { float f; unsigned int u; } c; c.f = f;
  unsigned int u = c.u + 0x7fffu + ((c.u >> 16) & 1u);  // RNE
  return (unsigned short)(u >> 16);
}
__device__ __forceinline__ float bf2f(unsigned short h) {
  union { unsigned int u; float f; } c; c.u = ((unsigned int)h) << 16;
  return c.f;
}
// async 16B global->LDS (direct-to-shared DMA); lds dest must be wave-uniform base
__device__ __forceinline__ void gll16(const unsigned short* g, unsigned short* l) {
  __builtin_amdgcn_global_load_lds(
      (const __attribute__((address_space(1))) unsigned int*)g,
      (__attribute__((address_space(3))) unsigned int*)l, 16, 0, 0);
}

// ---------------- kernel 1: row norms + normalized bf16 hi/lo planes ----------------
__global__ void rownorm_k(const float* __restrict__ z, double* __restrict__ inv64,
                          unsigned short* __restrict__ zhi, unsigned short* __restrict__ zlo) {
  const int w = threadIdx.x >> 6, lane = threadIdx.x & 63;
  const int row = blockIdx.x * 4 + w;
  const float4 v = *reinterpret_cast<const float4*>(z + (size_t)row * ND + lane * 4);
  double s = (double)v.x * v.x + (double)v.y * v.y + (double)v.z * v.z + (double)v.w * v.w;
  #pragma unroll
  for (int m = 32; m; m >>= 1) s += __shfl_xor(s, m, 64);
  double nrm = sqrt(s);
  if (nrm < 1e-12) nrm = 1e-12;
  const double inv = 1.0 / nrm;
  if (lane == 0) inv64[row] = inv;
  float nv[4] = {(float)(v.x * inv), (float)(v.y * inv), (float)(v.z * inv), (float)(v.w * inv)};
  ushort4 h, lo;
  h.x = f2bf(nv[0]); h.y = f2bf(nv[1]); h.z = f2bf(nv[2]); h.w = f2bf(nv[3]);
  lo.x = f2bf(nv[0] - bf2f(h.x)); lo.y = f2bf(nv[1] - bf2f(h.y));
  lo.z = f2bf(nv[2] - bf2f(h.z)); lo.w = f2bf(nv[3] - bf2f(h.w));
  *reinterpret_cast<ushort4*>(zhi + (size_t)row * ND + lane * 4) = h;
  *reinterpret_cast<ushort4*>(zlo + (size_t)row * ND + lane * 4) = lo;
}

// ---------------- kernel 2: code norms + bf16 hi/lo planes ----------------
__global__ void embnorm_k(const float* __restrict__ e, float* __restrict__ e2_32,
                          double* __restrict__ e2_64, unsigned short* __restrict__ ehi,
                          unsigned short* __restrict__ elo) {
  const int w = threadIdx.x >> 6, lane = threadIdx.x & 63;
  const int row = blockIdx.x * 4 + w;
  const float4 v = *reinterpret_cast<const float4*>(e + (size_t)row * ND + lane * 4);
  double s = (double)v.x * v.x + (double)v.y * v.y + (double)v.z * v.z + (double)v.w * v.w;
  #pragma unroll
  for (int m = 32; m; m >>= 1) s += __shfl_xor(s, m, 64);
  if (lane == 0) { e2_64[row] = s; e2_32[row] = (float)s; }
  ushort4 h, lo;
  h.x = f2bf(v.x); h.y = f2bf(v.y); h.z = f2bf(v.z); h.w = f2bf(v.w);
  lo.x = f2bf(v.x - bf2f(h.x)); lo.y = f2bf(v.y - bf2f(h.y));
  lo.z = f2bf(v.z - bf2f(h.z)); lo.w = f2bf(v.w - bf2f(h.w));
  *reinterpret_cast<ushort4*>(ehi + (size_t)row * ND + lane * 4) = h;
  *reinterpret_cast<ushort4*>(elo + (size_t)row * ND + lane * 4) = lo;
}

// ---------------- kernel 3: split-bf16 MFMA GEMM + argmin (+2nd best) ----------------
// 128 rows x 128 codes per block; 4 waves (2x2); acc = Ah*Bh + Ah*Bl + Al*Bh.
// LDS: 4 buffers [128 rows][64 k] bf16, unpadded (global_load_lds), XOR-seg swizzle.
#define MB 128
#define NB 128
#define BK 64
#define MARGIN 3e-4f

__launch_bounds__(256, 2)
__global__ void phase1_k(const unsigned short* __restrict__ zhi, const unsigned short* __restrict__ zlo,
                         const unsigned short* __restrict__ ehi, const unsigned short* __restrict__ elo,
                         const float* __restrict__ e2,
                         int* __restrict__ best_idx, int* __restrict__ rcount,
                         int* __restrict__ rrows) {
  __shared__ __align__(16) unsigned short smem[4 * MB * BK];  // 65536 B
  unsigned short* Ah = smem;
  unsigned short* Al = smem + MB * BK;
  unsigned short* Bh = smem + 2 * MB * BK;
  unsigned short* Bl = smem + 3 * MB * BK;

  const int t = threadIdx.x;
  const int l = t & 63;
  const int wave = t >> 6;
  const int wm = wave & 1;   // row half
  const int wn = wave >> 1;  // code half
  const int l15 = l & 15, l4 = l >> 4;
  const int row0 = blockIdx.x * MB;

  // staging geometry: LDS byte offset o = wave*4096 + j*1024 + l*16
  // -> row = o>>7, stored seg = (o>>4)&7, source seg = stored ^ (row&7)
  int rowo[4], sego[4];
  const unsigned short* asrcH[4];
  #pragma unroll
  for (int j = 0; j < 4; ++j) {
    const int o = wave * 4096 + j * 1024 + l * 16;
    rowo[j] = o >> 7;
    sego[j] = ((o >> 4) & 7) ^ (rowo[j] & 7);
    asrcH[j] = zhi + (size_t)(row0 + rowo[j]) * ND + sego[j] * 8;
  }

  float b1[16], b2[16];
  int i1[16];
  #pragma unroll
  for (int s = 0; s < 16; ++s) { b1[s] = 3.4e38f; b2[s] = 3.4e38f; i1[s] = 0; }

  for (int ct = 0; ct < NK / NB; ++ct) {
    const int cbase = ct * NB;
    f32x4 acc[4][4];
    #pragma unroll
    for (int mt = 0; mt < 4; ++mt)
      #pragma unroll
      for (int nt = 0; nt < 4; ++nt) acc[mt][nt] = (f32x4){0.f, 0.f, 0.f, 0.f};

    for (int ks = 0; ks < ND / BK; ++ks) {
      const int d0 = ks * BK;
      __syncthreads();
      #pragma unroll
      for (int j = 0; j < 4; ++j) {
        unsigned short* ldsA = Ah + wave * 2048 + j * 512;           // wave-uniform
        const size_t boff = (size_t)(cbase + rowo[j]) * ND + d0 + sego[j] * 8;
        gll16(asrcH[j] + d0,             ldsA);                      // Ah
        gll16(asrcH[j] + d0 + M_OUT,     ldsA + MB * BK);            // Al (zlo = zhi + M_OUT)
        gll16(ehi + boff,                ldsA + 2 * MB * BK);        // Bh
        gll16(elo + boff,                ldsA + 3 * MB * BK);        // Bl
      }
      __syncthreads();
      #pragma unroll
      for (int kk = 0; kk < 2; ++kk) {
        bf16x8 aH[4], aL[4], bH[4], bL[4];
        #pragma unroll
        for (int mt = 0; mt < 4; ++mt) {
          const int ar = wm * 64 + mt * 16 + l15;
          const int sg = (kk * 4 + l4) ^ (ar & 7);
          aH[mt] = *reinterpret_cast<const bf16x8*>(&Ah[ar * BK + sg * 8]);
          aL[mt] = *reinterpret_cast<const bf16x8*>(&Al[ar * BK + sg * 8]);
        }
        #pragma unroll
        for (int nt = 0; nt < 4; ++nt) {
          const int br = wn * 64 + nt * 16 + l15;
          const int sg = (kk * 4 + l4) ^ (br & 7);
          bH[nt] = *reinterpret_cast<const bf16x8*>(&Bh[br * BK + sg * 8]);
          bL[nt] = *reinterpret_cast<const bf16x8*>(&Bl[br * BK + sg * 8]);
        }
        #pragma unroll
        for (int mt = 0; mt < 4; ++mt)
          #pragma unroll
          for (int nt = 0; nt < 4; ++nt) {
            acc[mt][nt] = __builtin_amdgcn_mfma_f32_16x16x32_bf16(aH[mt], bH[nt], acc[mt][nt], 0, 0, 0);
            acc[mt][nt] = __builtin_amdgcn_mfma_f32_16x16x32_bf16(aH[mt], bL[nt], acc[mt][nt], 0, 0, 0);
            acc[mt][nt] = __builtin_amdgcn_mfma_f32_16x16x32_bf16(aL[mt], bH[nt], acc[mt][nt], 0, 0, 0);
          }
      }
    }
    // epilogue: score = e2 - 2*dot; per-lane best/2nd, ascending code order
    #pragma unroll
    for (int nt = 0; nt < 4; ++nt) {
      const int c = cbase + wn * 64 + nt * 16 + l15;
      const float e2c = e2[c];
      #pragma unroll
      for (int mt = 0; mt < 4; ++mt) {
        #pragma unroll
        for (int r = 0; r < 4; ++r) {
          const float s = fmaf(-2.0f, acc[mt][nt][r], e2c);
          const int slot = mt * 4 + r;
          if (s < b1[slot]) { b2[slot] = b1[slot]; b1[slot] = s; i1[slot] = c; }
          else if (s < b2[slot]) { b2[slot] = s; }
        }
      }
    }
  }

  // butterfly merge across the 16 lanes (l&15) sharing each row
  #pragma unroll
  for (int s = 0; s < 16; ++s) {
    #pragma unroll
    for (int m = 1; m < 16; m <<= 1) {
      const float ob1 = __shfl_xor(b1[s], m, 64);
      const float ob2 = __shfl_xor(b2[s], m, 64);
      const int oi1 = __shfl_xor(i1[s], m, 64);
      if (ob1 < b1[s] || (ob1 == b1[s] && oi1 < i1[s])) {
        b2[s] = fminf(b1[s], ob2);
        b1[s] = ob1; i1[s] = oi1;
      } else {
        b2[s] = fminf(b2[s], ob1);
      }
    }
  }

  // cross-wave (wn=0/1) merge via small LDS
  __syncthreads();
  float* M1 = (float*)smem;           // [128][2]
  float* M2 = M1 + 256;               // [128][2]
  int*   MI = (int*)(M1 + 512);       // [128][2]
  if (l15 == 0) {
    #pragma unroll
    for (int s = 0; s < 16; ++s) {
      const int mt = s >> 2, r = s & 3;
      const int rl = wm * 64 + mt * 16 + l4 * 4 + r;
      M1[rl * 2 + wn] = b1[s];
      M2[rl * 2 + wn] = b2[s];
      MI[rl * 2 + wn] = i1[s];
    }
  }
  __syncthreads();
  if (t < MB) {
    float B1 = M1[t * 2], B2 = M2[t * 2];
    int I1 = MI[t * 2];
    const float y1 = M1[t * 2 + 1], y2 = M2[t * 2 + 1];
    const int yi = MI[t * 2 + 1];
    if (y1 < B1 || (y1 == B1 && yi < I1)) {
      B2 = fminf(B1, y2);
      B1 = y1; I1 = yi;
    } else {
      B2 = fminf(B2, y1);
    }
    const int row = row0 + t;
    best_idx[row] = I1;
    if (B2 - B1 < MARGIN) {  // ambiguous at split-bf16 precision -> exact recheck
      const int pos = atomicAdd(rcount, 1);
      rrows[pos] = row;
    }
  }
}

// ---------------- kernel 4: exact fp64 recheck of flagged rows ----------------
__global__ void phase2_k(const float* __restrict__ z, const float* __restrict__ emb,
                         const double* __restrict__ e2_64, const double* __restrict__ inv64,
                         const int* __restrict__ rcount, const int* __restrict__ rrows,
                         int* __restrict__ best_idx) {
  __shared__ double zn[ND];
  __shared__ double RB[256];
  __shared__ int RI[256];
  const int t = threadIdx.x;
  int cnt = rcount[0];
  if (cnt > NROWS) cnt = NROWS;
  for (int e = blockIdx.x; e < cnt; e += gridDim.x) {
    const int row = rrows[e];
    __syncthreads();
    zn[t] = (double)z[(size_t)row * ND + t] * inv64[row];
    __syncthreads();
    double B1 = 1e300;
    int I1 = 0;
    for (int c0 = 0; c0 < 16; ++c0) {
      const int c = t * 16 + c0;  // ascending within thread -> lowest-index on tie
      const float* er = emb + (size_t)c * ND;
      double dot = 0.0;
      for (int d = 0; d < ND; d += 4) {
        const float4 ev = *reinterpret_cast<const float4*>(er + d);
        dot += zn[d] * (double)ev.x + zn[d + 1] * (double)ev.y +
               zn[d + 2] * (double)ev.z + zn[d + 3] * (double)ev.w;
      }
      const double s = e2_64[c] - 2.0 * dot;
      if (s < B1) { B1 = s; I1 = c; }
    }
    RB[t] = B1; RI[t] = I1;
    __syncthreads();
    for (int off = 128; off; off >>= 1) {
      if (t < off) {
        const double sb = RB[t + off];
        const int si = RI[t + off];
        if (sb < RB[t] || (sb == RB[t] && si < RI[t])) { RB[t] = sb; RI[t] = si; }
      }
      __syncthreads();
    }
    if (t == 0) best_idx[row] = RI[0];
  }
}

// ---------------- kernel 5: gather z_q, loss partials, histogram, index output ----------------
__global__ void gather_k(const float* __restrict__ z, const float* __restrict__ emb,
                         const int* __restrict__ best_idx, const double* __restrict__ inv64,
                         float* __restrict__ out, double* __restrict__ partials,
                         int* __restrict__ counts) {
  __shared__ double wsum[4];
  const int w = threadIdx.x >> 6, lane = threadIdx.x & 63;
  const int row = blockIdx.x * 4 + w;
  const int idx = best_idx[row];
  const double inv = inv64[row];
  const float4 zv = *reinterpret_cast<const float4*>(z + (size_t)row * ND + lane * 4);
  const float4 ev = *reinterpret_cast<const float4*>(emb + (size_t)idx * ND + lane * 4);
  *reinterpret_cast<float4*>(out + (size_t)row * ND + lane * 4) = ev;  // z_q_st == z_q
  const double dx = (double)ev.x - (double)zv.x * inv;
  const double dy = (double)ev.y - (double)zv.y * inv;
  const double dz = (double)ev.z - (double)zv.z * inv;
  const double dw = (double)ev.w - (double)zv.w * inv;
  double s = dx * dx + dy * dy + dz * dz + dw * dw;
  #pragma unroll
  for (int m = 32; m; m >>= 1) s += __shfl_xor(s, m, 64);
  if (lane == 0) {
    wsum[w] = s;
    atomicAdd(&counts[idx], 1);
    out[IDX_OFF + row] = (float)idx;
  }
  __syncthreads();
  if (threadIdx.x == 0) partials[blockIdx.x] = wsum[0] + wsum[1] + wsum[2] + wsum[3];
}

// ---------------- kernel 6: scalars (losses + perplexity) ----------------
__global__ void finalize_k(const double* __restrict__ partials, const int* __restrict__ counts,
                           float* __restrict__ out) {
  __shared__ double red[256];
  const int t = threadIdx.x;
  double s = 0.0;
  for (int k = 0; k < 64; ++k) s += partials[t + 256 * k];
  red[t] = s;
  __syncthreads();
  for (int off = 128; off; off >>= 1) {
    if (t < off) red[t] += red[t + off];
    __syncthreads();
  }
  const double c = red[0] / (double)M_OUT;  // codebook_loss == commitment_loss
  __syncthreads();
  double h = 0.0;
  for (int k = 0; k < 16; ++k) {
    const double p = (double)counts[t * 16 + k] * (1.0 / 65536.0);
    h += p * log(p + 1e-10);
  }
  red[t] = h;
  __syncthreads();
  for (int off = 128; off; off >>= 1) {
    if (t < off) red[t] += red[t + off];
    __syncthreads();
  }
  if (t == 0) {
    const double perp = exp(-red[0]);
    out[M_OUT + 0] = (float)(c + 0.25 * c);  // vq_loss = codebook + BETA*commitment
    out[M_OUT + 1] = (float)c;               // codebook_loss
    out[M_OUT + 2] = (float)c;               // commitment_loss
    out[M_OUT + 3] = (float)perp;            // perplexity
  }
}

extern "C" void kernel_launch(void* const* d_in, const int* in_sizes, int n_in,
                              void* d_out, int out_size, void* d_ws, size_t ws_size,
                              hipStream_t stream) {
  const float* z = (const float*)d_in[0];
  const float* emb = (const float*)d_in[1];
  float* out = (float*)d_out;
  char* ws = (char*)d_ws;
  double* inv64   = (double*)(ws + WS_INV64);
  float*  e2_32   = (float*)(ws + WS_E2_32);
  double* e2_64   = (double*)(ws + WS_E2_64);
  unsigned short* ehi = (unsigned short*)(ws + WS_EHI);
  unsigned short* elo = (unsigned short*)(ws + WS_ELO);
  int*    best_i  = (int*)(ws + WS_BESTIDX);
  int*    counts  = (int*)(ws + WS_COUNTS);
  int*    rcount  = (int*)(ws + WS_RCOUNT);
  int*    rrows   = (int*)(ws + WS_RROWS);
  double* partials = (double*)(ws + WS_PART);
  // z hi/lo planes live in d_out[0..16M floats) -- fully overwritten by gather_k later
  unsigned short* zhi = (unsigned short*)d_out;         // [65536][256]
  unsigned short* zlo = zhi + M_OUT;                    // [65536][256]

  hipMemsetAsync(ws + WS_COUNTS, 0, 16 * 1024 + 16, stream);  // counts + rcount
  rownorm_k<<<NROWS / 4, 256, 0, stream>>>(z, inv64, zhi, zlo);
  embnorm_k<<<NK / 4, 256, 0, stream>>>(emb, e2_32, e2_64, ehi, elo);
  phase1_k<<<NROWS / MB, 256, 0, stream>>>(zhi, zlo, ehi, elo, e2_32, best_i, rcount, rrows);
  phase2_k<<<1024, 256, 0, stream>>>(z, emb, e2_64, inv64, rcount, rrows, best_i);
  gather_k<<<NROWS / 4, 256, 0, stream>>>(z, emb, best_i, inv64, out, partials, counts);
  finalize_k<<<1, 256, 0, stream>>>(partials, counts, out);
}